// Round 8
// baseline (20.688 us; speedup 1.0000x reference)
//
#include <hip/hip_runtime.h>

#define NUM_EMBEDDINGS 50000
#define EMBEDDING_DIM  1024
#define N_CENTROIDS    256
#define N_BLOCKS       128    // EMBEDDING_DIM / 8
#define N_TOKENS       16384  // BATCH * SEQ
#define N_PARTS        8      // one per XCD
#define BLKS_PER_PART  (N_BLOCKS / N_PARTS)   // 16
#define TOK_PER_TGRP   8      // sequential tokens per 32-lane group

typedef float f32x4 __attribute__((ext_vector_type(4)));

// R5 structure (XCD-sliced code reads + nt stores) + SEQUENTIAL 8-token loop.
//
//   part = bid & 7  -> fixed XCD; L2 caches blks [16p,16p+16) of assignments
//                      (3.2 MB < 4 MB), protected from eviction by nt stores.
//   Each 32-lane group handles 8 CONSECUTIVE tokens in a loop (unroll 2):
//   amortizes wave launch/ramp over 8 store bursts instead of 1 (R5), while
//   keeping only ~2 scattered-gather chains in flight (R6's 8-parallel
//   batching oversubscribed the outstanding-miss queue and regressed).
//
//   Per iteration: id (64 KB table, L2-hot, broadcast) -> code (4 B scattered,
//   XCD-local L2) -> centroid float4 (8 KB, L1-hot) -> nt store 512 B/group.
__global__ __launch_bounds__(256) void pq_embed_loop_kernel(
    const float* __restrict__ centroids,     // [256][8]
    const int*   __restrict__ assignments,   // [128][50000]
    const int*   __restrict__ input_ids,     // [16384]
    float*       __restrict__ out)           // [16384][1024]
{
    const int part  = blockIdx.x & (N_PARTS - 1);
    const int group = blockIdx.x >> 3;

    const int tid  = threadIdx.x;
    const int tgrp = tid >> 5;
    const int lane = tid & 31;

    const int blk    = part * BLKS_PER_PART + (lane >> 1);
    const int half   = lane & 1;
    const int token0 = group * (8 * TOK_PER_TGRP) + tgrp * TOK_PER_TGRP;

    const int*   __restrict__ arow = assignments + (size_t)blk * NUM_EMBEDDINGS;
    const f32x4* __restrict__ c4   = reinterpret_cast<const f32x4*>(centroids);
    f32x4*       __restrict__ o4   = reinterpret_cast<f32x4*>(out) +
                                     (size_t)token0 * (EMBEDDING_DIM / 4) +
                                     part * 32 + lane;

    #pragma unroll 2
    for (int k = 0; k < TOK_PER_TGRP; ++k) {
        const int id   = input_ids[token0 + k];
        const int code = arow[id];
        const f32x4 v  = c4[(code << 1) + half];
        __builtin_nontemporal_store(v, o4 + (size_t)k * (EMBEDDING_DIM / 4));
    }
}

extern "C" void kernel_launch(void* const* d_in, const int* in_sizes, int n_in,
                              void* d_out, int out_size, void* d_ws, size_t ws_size,
                              hipStream_t stream) {
    const float* centroids   = (const float*)d_in[0];
    const int*   assignments = (const int*)d_in[1];
    const int*   input_ids   = (const int*)d_in[2];
    float*       out         = (float*)d_out;

    // 16384 tokens / 64 tokens-per-block * 8 parts = 2048 blocks (8/CU)
    dim3 grid((N_TOKENS / (8 * TOK_PER_TGRP)) * N_PARTS);
    dim3 block(256);
    pq_embed_loop_kernel<<<grid, block, 0, stream>>>(centroids, assignments, input_ids, out);
}